// Round 10
// baseline (233.338 us; speedup 1.0000x reference)
//
#include <hip/hip_runtime.h>

// Problem constants
constexpr int   kAtoms  = 5000;
constexpr int   kPairs  = 160000;
constexpr int   KD      = 128;   // K
constexpr int   NB      = 8;     // N_BASIS
constexpr int   RH      = 32;    // RAD_HIDDEN
constexpr float kCutoff = 5.0f;
constexpr float kPi     = 3.14159265358979323846f;
constexpr float C1 = 0.2f * 0.1767767f;   // INIT_SCALE * MSG_SCALE
constexpr float C2 = 1.2f * 0.1767767f;   // (1+INIT_SCALE) * MSG_SCALE

__device__ __forceinline__ float silu(float x) { return x / (1.0f + __expf(-x)); }
__device__ __forceinline__ void wave_fence() { __builtin_amdgcn_wave_barrier(); }

// Only the l=0 channel reaches the output; l>=1 / sph / U2 are dead code.
//   F0[a][k] = C1 * sum_p R0_p[k]*e_spec[k];  G0 = F0+F0^2*mix
//   D[a][k]  = sum_p Re0_p[k]*G0[nbr_p][k];   n = G0+C2*D;  V = n+n^2*emix
//   out = head MLP(V)
// 4 dispatches: csr (LDS hist+scan) -> build (rbf + erad-hidden h2, CSR order)
//   -> f0 (LDS-staged rbf, species-factored) -> d0+head (LDS-staged h2).

// ---------------------------------------------------------------------------
// K1: CSR setup in one block: LDS histogram of ctr, then exclusive scan.
// ---------------------------------------------------------------------------
__global__ __launch_bounds__(1024) void csr_kernel(
    const int* __restrict__ ctr, int* __restrict__ off, int* __restrict__ cur)
{
    __shared__ int lcnt[kAtoms];
    __shared__ int s_part[1024];
    int t = threadIdx.x;
    for (int i = t; i < kAtoms; i += 1024) lcnt[i] = 0;
    __syncthreads();
    for (int p = t; p < kPairs; p += 1024) atomicAdd(&lcnt[ctr[p]], 1);
    __syncthreads();

    const int CH = 5;                       // 1024*5 = 5120 >= 5000
    int base = t * CH, loc[CH], run = 0;
    #pragma unroll
    for (int i = 0; i < CH; i++) {
        int idx = base + i;
        int v = (idx < kAtoms) ? lcnt[idx] : 0;
        loc[i] = run; run += v;
    }
    s_part[t] = run;
    __syncthreads();
    for (int st = 1; st < 1024; st <<= 1) {
        int v = (t >= st) ? s_part[t - st] : 0;
        __syncthreads(); s_part[t] += v; __syncthreads();
    }
    int excl = (t > 0) ? s_part[t - 1] : 0;
    #pragma unroll
    for (int i = 0; i < CH; i++) {
        int idx = base + i;
        if (idx < kAtoms) { off[idx] = excl + loc[i]; cur[idx] = excl + loc[i]; }
    }
    if (t == 1023) off[kAtoms] = s_part[1023];
}

// ---------------------------------------------------------------------------
// K2: build rbf (for f0) + erad hidden h2 (for d0) in CSR slot order.
// ---------------------------------------------------------------------------
__global__ __launch_bounds__(256) void build_kernel(
    const float* __restrict__ pos, const float* __restrict__ cells,
    const int* __restrict__ species, const int* __restrict__ shifts,
    const int* __restrict__ ctr, const int* __restrict__ nbr,
    const int* __restrict__ spair,
    const float* __restrict__ ew1, const float* __restrict__ eb1,
    int* __restrict__ cur, int* __restrict__ nbrs_s, int* __restrict__ specs_s,
    float* __restrict__ rbf_s, float* __restrict__ h2buf)
{
    int p = blockIdx.x * 256 + threadIdx.x;
    int ci = ctr[p], ni = nbr[p], sp = spair[p];
    float s0 = (float)shifts[p * 3 + 0] - 1.0f;
    float s1 = (float)shifts[p * 3 + 1] - 1.0f;
    float s2 = (float)shifts[p * 3 + 2] - 1.0f;
    const float* C = cells + sp * 9;
    float vx = pos[ni * 3 + 0] - pos[ci * 3 + 0] + s0 * C[0] + s1 * C[3] + s2 * C[6];
    float vy = pos[ni * 3 + 1] - pos[ci * 3 + 1] + s0 * C[1] + s1 * C[4] + s2 * C[7];
    float vz = pos[ni * 3 + 2] - pos[ci * 3 + 2] + s0 * C[2] + s1 * C[5] + s2 * C[8];
    float d = sqrtf(vx * vx + vy * vy + vz * vz + 1e-12f);
    float fcut = (d < kCutoff) ? 0.5f * (__cosf(kPi * d / kCutoff) + 1.0f) : 0.0f;

    int slot = atomicAdd(cur + ci, 1);
    nbrs_s[slot]  = ni;
    specs_s[slot] = species[ni];

    float r[NB];
    #pragma unroll
    for (int i = 0; i < NB; i++) {
        float tt = d - (kCutoff / (NB - 1)) * (float)i;
        r[i] = __expf(-2.0f * tt * tt) * fcut;
    }
    float4* rdst = (float4*)(rbf_s + (size_t)slot * NB);
    rdst[0] = make_float4(r[0], r[1], r[2], r[3]);
    rdst[1] = make_float4(r[4], r[5], r[6], r[7]);

    float* hdst = h2buf + (size_t)slot * RH;
    #pragma unroll
    for (int jq = 0; jq < RH / 4; jq++) {
        float4 hv; float* pv = (float*)&hv;
        #pragma unroll
        for (int u = 0; u < 4; u++) {
            int j = 4 * jq + u;
            float acc = eb1[j];
            #pragma unroll
            for (int i = 0; i < NB; i++) acc += r[i] * ew1[i * RH + j];
            pv[u] = silu(acc);
        }
        *(float4*)(hdst + 4 * jq) = hv;
    }
}

// ---------------------------------------------------------------------------
// K3: species-factored F0 + G0. 4 waves/block, wave = atom.
// rbf staged per 32-pair chunk into wave-private LDS (coalesced dwordx4).
// ---------------------------------------------------------------------------
__global__ __launch_bounds__(256) void f0_kernel(
    const float* __restrict__ rbf_s, const int* __restrict__ specs_s,
    const int* __restrict__ off,
    const float* __restrict__ embed,
    const float* __restrict__ w1, const float* __restrict__ b1,
    const float* __restrict__ w2, const float* __restrict__ b2,
    const float* __restrict__ mix,
    float* __restrict__ G0)
{
    __shared__ float s_w1[NB][RH];
    __shared__ float s_b1v[RH];
    __shared__ float s_rb[4][32][NB];   // per-wave 32-pair rbf chunk (1 KB each)
    __shared__ int   s_sp[4][32];
    __shared__ float s_H[4][4][RH];     // [wave][spec][j]

    int t = threadIdx.x, w = t >> 6, lane = t & 63;
    for (int idx = t; idx < NB * RH; idx += 256)
        s_w1[idx >> 5][idx & 31] = w1[idx];
    if (t < RH) s_b1v[t] = b1[t];
    __syncthreads();

    int a = blockIdx.x * 4 + w;          // 5000 = 4*1250
    int start = off[a], end = off[a + 1];

    int g = lane >> 5, j = lane & 31;
    float b1j = s_b1v[j];
    float H0 = 0, H1 = 0, H2 = 0, H3 = 0;
    int   n0 = 0, n1 = 0, n2 = 0, n3 = 0;

    for (int c = start; c < end; c += 32) {
        int mm = min(32, end - c);
        // coalesced stage: 32 pairs * 8 floats = 256 floats = 64 lanes * float4
        float4 rv = *((const float4*)(rbf_s + (size_t)c * NB) + lane);
        ((float4*)s_rb[w])[lane] = rv;
        if (lane < mm) s_sp[w][lane] = specs_s[c + lane];
        wave_fence();
        for (int pr = g; pr < mm; pr += 2) {
            const float* rb = s_rb[w][pr];
            float acc = b1j;
            #pragma unroll
            for (int i = 0; i < NB; i++) acc += rb[i] * s_w1[i][j];
            float h = silu(acc);
            int s = s_sp[w][pr];
            H0 += (s == 0) ? h : 0.0f;  H1 += (s == 1) ? h : 0.0f;
            H2 += (s == 2) ? h : 0.0f;  H3 += (s == 3) ? h : 0.0f;
            n0 += (s == 0); n1 += (s == 1); n2 += (s == 2); n3 += (s == 3);
        }
        wave_fence();
    }
    // combine the two g-halves in-register
    H0 += __shfl_xor(H0, 32); H1 += __shfl_xor(H1, 32);
    H2 += __shfl_xor(H2, 32); H3 += __shfl_xor(H3, 32);
    n0 += __shfl_xor(n0, 32); n1 += __shfl_xor(n1, 32);
    n2 += __shfl_xor(n2, 32); n3 += __shfl_xor(n3, 32);
    if (lane < 32) {
        s_H[w][0][j] = H0; s_H[w][1][j] = H1;
        s_H[w][2][j] = H2; s_H[w][3][j] = H3;
    }
    wave_fence();
    float fn0 = (float)n0, fn1 = (float)n1, fn2 = (float)n2, fn3 = (float)n3;

    #pragma unroll
    for (int half = 0; half < 2; half++) {
        int k = lane + 64 * half;
        float e0 = embed[0 * KD + k], e1 = embed[1 * KD + k];
        float e2 = embed[2 * KD + k], e3 = embed[3 * KD + k];
        float P0 = 0, P1 = 0, P2 = 0, P3 = 0;
        #pragma unroll
        for (int jq = 0; jq < RH / 4; jq++) {
            float4 h0 = *(const float4*)&s_H[w][0][4 * jq];
            float4 h1 = *(const float4*)&s_H[w][1][4 * jq];
            float4 h2 = *(const float4*)&s_H[w][2][4 * jq];
            float4 h3 = *(const float4*)&s_H[w][3][4 * jq];
            float wa = w2[(4 * jq + 0) * (3 * KD) + k];
            float wb = w2[(4 * jq + 1) * (3 * KD) + k];
            float wc = w2[(4 * jq + 2) * (3 * KD) + k];
            float wd = w2[(4 * jq + 3) * (3 * KD) + k];
            P0 += h0.x * wa + h0.y * wb + h0.z * wc + h0.w * wd;
            P1 += h1.x * wa + h1.y * wb + h1.z * wc + h1.w * wd;
            P2 += h2.x * wa + h2.y * wb + h2.z * wc + h2.w * wd;
            P3 += h3.x * wa + h3.y * wb + h3.z * wc + h3.w * wd;
        }
        float F = b2[k] * (fn0 * e0 + fn1 * e1 + fn2 * e2 + fn3 * e3)
                + e0 * P0 + e1 * P1 + e2 * P2 + e3 * P3;
        float F0v = C1 * F;
        G0[(size_t)a * KD + k] = F0v + F0v * F0v * mix[k];
    }
}

// ---------------------------------------------------------------------------
// K4: d0 + head. 4 waves/block, wave = atom (lane = k-pair 2l, 2l+1).
// h2 staged per 32-pair chunk into wave-private LDS (4 coalesced dwordx4),
// then broadcast-read; G0 gathered as dwordx2. Head fused on the 4 atoms.
// ---------------------------------------------------------------------------
__global__ __launch_bounds__(256) void d0head_kernel(
    const float* __restrict__ h2buf, const int* __restrict__ nbrs_s,
    const int* __restrict__ off,
    const float* __restrict__ w2, const float* __restrict__ b2,
    const float* __restrict__ emix,
    const float* __restrict__ G0,
    const float* __restrict__ hw1, const float* __restrict__ hb1,
    const float* __restrict__ hw2, const float* __restrict__ hb2,
    const float* __restrict__ lw, const float* __restrict__ lb,
    float* __restrict__ out)
{
    __shared__ float s_h[4][32][RH];    // 16 KB: per-wave 32-pair h2 chunk
    __shared__ int   s_nbr[4][32];
    __shared__ float s_v[4][KD];
    __shared__ float s_m[4][KD];

    int t = threadIdx.x, w = t >> 6, lane = t & 63;
    int a = blockIdx.x * 4 + w;
    int start = off[a], end = off[a + 1];

    int k0 = 2 * lane, k1 = 2 * lane + 1;
    float w2c0[RH], w2c1[RH];
    #pragma unroll
    for (int j = 0; j < RH; j++) {
        float2 wv = *(const float2*)&w2[j * (3 * KD) + k0];
        w2c0[j] = wv.x; w2c1[j] = wv.y;
    }
    float b2k0 = b2[k0], b2k1 = b2[k1];

    float D0 = 0.0f, D1 = 0.0f;
    for (int c = start; c < end; c += 32) {
        int mm = min(32, end - c);
        // coalesced stage: 32 pairs * 32 floats = 1024 floats = 4 * (64 lanes * float4)
        const float4* src = (const float4*)(h2buf + (size_t)c * RH);
        #pragma unroll
        for (int q = 0; q < 4; q++)
            ((float4*)s_h[w])[q * 64 + lane] = src[q * 64 + lane];
        if (lane < mm) s_nbr[w][lane] = nbrs_s[c + lane];
        wave_fence();
        #pragma unroll 2
        for (int i = 0; i < mm; i++) {
            int nb = s_nbr[w][i];
            float2 gv = *(const float2*)(G0 + (size_t)nb * KD + k0);
            float R0 = b2k0, R1 = b2k1;
            #pragma unroll
            for (int q = 0; q < RH / 4; q++) {
                float4 h4 = *(const float4*)&s_h[w][i][4 * q];
                R0 += h4.x * w2c0[4*q+0] + h4.y * w2c0[4*q+1]
                    + h4.z * w2c0[4*q+2] + h4.w * w2c0[4*q+3];
                R1 += h4.x * w2c1[4*q+0] + h4.y * w2c1[4*q+1]
                    + h4.z * w2c1[4*q+2] + h4.w * w2c1[4*q+3];
            }
            D0 += R0 * gv.x;
            D1 += R1 * gv.y;
        }
        wave_fence();
    }
    {
        float2 ga = *(const float2*)(G0 + (size_t)a * KD + k0);
        float q0 = ga.x + C2 * D0, q1 = ga.y + C2 * D1;
        s_v[w][k0] = q0 + q0 * q0 * emix[k0];
        s_v[w][k1] = q1 + q1 * q1 * emix[k1];
    }
    __syncthreads();

    // ---- head: 2 thread-groups x 128 j; each group handles 2 atoms --------
    int j = t & 127, grp = t >> 7;
    int a0 = grp * 2, a1 = grp * 2 + 1;
    float acc0 = hb1[j], acc1 = acc0;
    for (int kk = 0; kk < KD; kk += 4) {
        float wa = hw1[(kk+0)*KD+j], wb = hw1[(kk+1)*KD+j];
        float wc = hw1[(kk+2)*KD+j], wd = hw1[(kk+3)*KD+j];
        float4 v0 = *(const float4*)&s_v[a0][kk];
        float4 v1 = *(const float4*)&s_v[a1][kk];
        acc0 += v0.x*wa + v0.y*wb + v0.z*wc + v0.w*wd;
        acc1 += v1.x*wa + v1.y*wb + v1.z*wc + v1.w*wd;
    }
    s_m[a0][j] = silu(acc0);
    s_m[a1][j] = silu(acc1);
    __syncthreads();
    acc0 = hb2[j]; acc1 = acc0;
    for (int kk = 0; kk < KD; kk += 4) {
        float wa = hw2[(kk+0)*KD+j], wb = hw2[(kk+1)*KD+j];
        float wc = hw2[(kk+2)*KD+j], wd = hw2[(kk+3)*KD+j];
        float4 v0 = *(const float4*)&s_m[a0][kk];
        float4 v1 = *(const float4*)&s_m[a1][kk];
        acc0 += v0.x*wa + v0.y*wb + v0.z*wc + v0.w*wd;
        acc1 += v1.x*wa + v1.y*wb + v1.z*wc + v1.w*wd;
    }
    float lwj = lw[j];
    __syncthreads();
    s_v[a0][j] = silu(acc0) * lwj;
    s_v[a1][j] = silu(acc1) * lwj;
    __syncthreads();
    for (int s = 64; s > 0; s >>= 1) {
        if (j < s) {
            s_v[a0][j] += s_v[a0][j + s];
            s_v[a1][j] += s_v[a1][j + s];
        }
        __syncthreads();
    }
    if (t < 4) out[blockIdx.x * 4 + t] = s_v[t][0] + lb[0];
}

// ---------------------------------------------------------------------------
extern "C" void kernel_launch(void* const* d_in, const int* in_sizes, int n_in,
                              void* d_out, int out_size, void* d_ws, size_t ws_size,
                              hipStream_t stream) {
    const float* positions = (const float*)d_in[0];
    const float* cells     = (const float*)d_in[1];
    const int*   species   = (const int*)d_in[2];
    const int*   shifts    = (const int*)d_in[3];
    const int*   ctr       = (const int*)d_in[4];
    const int*   nbr       = (const int*)d_in[5];
    const int*   spair     = (const int*)d_in[6];
    const float* embed     = (const float*)d_in[7];
    const float* rad_w1    = (const float*)d_in[8];
    const float* rad_b1    = (const float*)d_in[9];
    const float* rad_w2    = (const float*)d_in[10];
    const float* rad_b2    = (const float*)d_in[11];
    const float* erad_w1   = (const float*)d_in[12];
    const float* erad_b1   = (const float*)d_in[13];
    const float* erad_w2   = (const float*)d_in[14];
    const float* erad_b2   = (const float*)d_in[15];
    const float* mix_a     = (const float*)d_in[16];
    const float* emix_a    = (const float*)d_in[17];
    const float* head_w1   = (const float*)d_in[18];
    const float* head_b1   = (const float*)d_in[19];
    const float* head_w2   = (const float*)d_in[20];
    const float* head_b2   = (const float*)d_in[21];
    const float* last_w    = (const float*)d_in[22];
    const float* last_b    = (const float*)d_in[23];
    // U2 (d_in[24]) unused: l>=1 channels are dead code for the output.

    // layout: rbf and h2buf may be over-read by staging (up to 4 KB) — both
    // are followed by other ws allocations, so overshoot stays in-bounds.
    float* rbf_s = (float*)d_ws;                          // 160000*8  = 5.12 MB
    float* h2buf = rbf_s + (size_t)kPairs * NB;           // 160000*32 = 20.48 MB
    float* G0    = h2buf + (size_t)kPairs * RH;           // 5000*128  = 2.56 MB
    int*   off   = (int*)(G0 + (size_t)kAtoms * KD);      // 5001
    int*   cur   = off + kAtoms + 1;                      // 5000
    int*   nbrs  = cur + kAtoms;                          // 160000
    int*   specs = nbrs + kPairs;                         // 160000

    csr_kernel<<<1, 1024, 0, stream>>>(ctr, off, cur);

    build_kernel<<<kPairs / 256, 256, 0, stream>>>(
        positions, cells, species, shifts, ctr, nbr, spair,
        erad_w1, erad_b1, cur, nbrs, specs, rbf_s, h2buf);

    f0_kernel<<<kAtoms / 4, 256, 0, stream>>>(
        rbf_s, specs, off, embed, rad_w1, rad_b1, rad_w2, rad_b2,
        mix_a, G0);

    d0head_kernel<<<kAtoms / 4, 256, 0, stream>>>(
        h2buf, nbrs, off, erad_w2, erad_b2, emix_a, G0,
        head_w1, head_b1, head_w2, head_b2, last_w, last_b,
        (float*)d_out);
}